// Round 9
// baseline (275.088 us; speedup 1.0000x reference)
//
#include <hip/hip_runtime.h>
#include <hip/hip_bf16.h>

// ---------------------------------------------------------------------------
// Pipelined MFMA LSTM (B=8192,T=200,IN=4,H=16) + fused MLP (3200->64->28).
//   - block = 4 waves = one 16-sample group; wave l owns layer l AND MLP tile l
//   - software pipeline over timestep QUADS: superstep n, wave l computes
//     t = 4(n-l)..4(n-l)+3; ONE barrier per 4 timesteps (54 total)
//   - h in LDS as PRE-SPLIT bf16 hi/lo interleaved rows (80B stride)
//   - RATIONAL-FUSED activations: sig(i)*tanh(g) = (2-Dg)/(Di*Dg),
//     sig(o)*tanh(c) = (2-Dc)/(Do*Dc), D = 1+exp2(pre): 12 rcp/step vs 20
//     (c clamped to +-10 before tanh-exp2: rational form would NaN on overflow)
//   - x pre-split to bf16 hi/lo planes in d_ws: wave0 loads 2xb64/step
//     instead of ~28 VALU of runtime packing (straggler removal)
//   - W1 pre-split planes in d_ws, loaded at top of consuming superstep
//   - per layer: G[64,32] = [Wih|Whh] @ [h_{l-1};h_l] via mfma_f32_16x16x32_bf16
//     (3-term trunc hi/lo bf16 split, fp32-grade)
// ---------------------------------------------------------------------------

typedef short  bf16x8 __attribute__((ext_vector_type(8)));
typedef float  f32x4  __attribute__((ext_vector_type(4)));
typedef unsigned int uint2v __attribute__((ext_vector_type(2)));

namespace {
constexpr int kT    = 200;
constexpr int kOut  = 28;
constexpr int kQ    = kT / 4;          // 50 quads
constexpr int kSteps = kQ + 4;         // 54 (even)
constexpr float kNLog2e  = -1.4426950408889634f;   // -log2(e)
constexpr float kN2Log2e = -2.8853900817779268f;   // -2*log2(e)
constexpr int kW1Elems = 64 * 3200;
constexpr int kXElems  = 8192 * 200 * 4;
// H geometry (ushort units)
constexpr int kRow  = 40;              // per-sample row: hi8|hi8|lo8|lo8|pad8
constexpr int kSlot = 16 * kRow;       // 640
constexpr int kLay  = 4 * kSlot;       // 2560
constexpr int kPar  = 4 * kLay;        // 10240
}

union FragU { bf16x8 v; unsigned u[4]; };

__device__ __forceinline__ float fast_rcp(float v){ return __builtin_amdgcn_rcpf(v); }
__device__ __forceinline__ float fast_exp2(float v){ return __builtin_amdgcn_exp2f(v); }

// trunc-split 8 f32 -> bf16 hi frag + bf16 lo frag
__device__ __forceinline__ void split8(const float* v, FragU& hi, FragU& lo){
#pragma unroll
  for (int r=0;r<4;++r){
    unsigned ua=__float_as_uint(v[2*r]), ub=__float_as_uint(v[2*r+1]);
    hi.u[r] = (ua>>16) | (ub & 0xffff0000u);
    float af=__uint_as_float(ua & 0xffff0000u);
    float bf=__uint_as_float(ub & 0xffff0000u);
    float al=v[2*r]-af, bl=v[2*r+1]-bf;
    lo.u[r] = (__float_as_uint(al)>>16) | (__float_as_uint(bl) & 0xffff0000u);
  }
}

__global__ __launch_bounds__(256)
void presplit_pair(const float* __restrict__ src, int n,
                   short* __restrict__ dh, short* __restrict__ dl){
  int i = blockIdx.x*256 + threadIdx.x;
  if (i < n){
    float v = src[i];
    unsigned u = __float_as_uint(v);
    float hif = __uint_as_float(u & 0xffff0000u);
    float lo  = v - hif;
    dh[i] = (short)(u >> 16);
    dl[i] = (short)(__float_as_uint(lo) >> 16);
  }
}

template<bool PS>
__global__ __launch_bounds__(256)
void lstm_pipe(const float* __restrict__ x,     // [B,T,4]
               const float* __restrict__ Wih0,  // [64,4]
               const float* __restrict__ Wihr,  // [3,64,16]
               const float* __restrict__ Whh,   // [4,64,16]
               const float* __restrict__ bih,   // [4,64]
               const float* __restrict__ bhh,   // [4,64]
               const float* __restrict__ W1,    // [64,3200]
               const float* __restrict__ b1,    // [64]
               const float* __restrict__ W2,    // [28,64]
               const float* __restrict__ b2,    // [28]
               const short* __restrict__ W1h,   // [64,3200] bf16 hi plane
               const short* __restrict__ W1l,   // [64,3200] bf16 lo plane
               const short* __restrict__ Xh,    // [B,T,4] bf16 hi plane
               const short* __restrict__ Xl,    // [B,T,4] bf16 lo plane
               float* __restrict__ out)         // [B,28]
{
  __shared__ unsigned short H[2*kPar];   // packed h (hi/lo interleaved rows)
  __shared__ float ldsR[16][68];         // relu(hid), padded

  const int tid  = threadIdx.x;
  const int lane = tid & 63;
  const int wv   = tid >> 6;            // 0..3: layer index AND mlp tile index
  const int s    = lane & 15;           // sample within group (= MFMA col)
  const int q    = lane >> 4;           // lane quadrant (= k-chunk / row group)
  const int l    = wv;
  const int lm1  = (l==0) ? 0 : (l-1);
  const int sbase = blockIdx.x * 16;

  for (int i = tid; i < 2*kPar/2; i += 256) ((unsigned*)H)[i] = 0u;

  // ---- A fragments for THIS wave's layer: row=lane&15, k=q*8+e, tile=gate
  FragU A[4][2];
#pragma unroll
  for (int tile=0;tile<4;++tile){
    const int grow = tile*16 + s;
    const float kE = (tile==2)? kN2Log2e : kNLog2e;
    float v[8];
    if (l==0){
#pragma unroll
      for (int e=0;e<8;++e){
        float w = 0.f;
        if (q==0 && e<4) w = Wih0[grow*4+e];
        if (q>=2)        w = Whh[grow*16 + (q&1)*8 + e];
        v[e] = w*kE;
      }
    } else {
#pragma unroll
      for (int e=0;e<8;++e){
        float w = (q<2) ? Wihr[((l-1)*64+grow)*16 + q*8 + e]
                        : Whh [(( l )*64+grow)*16 + (q&1)*8 + e];
        v[e] = w*kE;
      }
    }
    split8(v, A[tile][0], A[tile][1]);
  }

  // ---- scaled bias in VGPRs (C-init)
  f32x4 biasf[4];
#pragma unroll
  for (int tile=0;tile<4;++tile){
    const float kE = (tile==2)? kN2Log2e : kNLog2e;
#pragma unroll
    for (int r=0;r<4;++r){
      const int row = l*64 + tile*16 + 4*q + r;
      biasf[tile][r] = (bih[row] + bhh[row]) * kE;
    }
  }

  float cst[4] = {0.f,0.f,0.f,0.f};
  f32x4 mlpacc = (f32x4){0.f,0.f,0.f,0.f};

  // ---- x: presplit bf16 planes (PS) or fp32 + runtime pack (!PS)
  const float* xp  = x  + (size_t)(sbase+s)*(kT*4);
  const short* xhp = PS ? (Xh + (size_t)(sbase+s)*(kT*4)) : nullptr;
  const short* xlp = PS ? (Xl + (size_t)(sbase+s)*(kT*4)) : nullptr;
  uint2v xh_[4], xl_[4];                 // current quad (PS, wave 0)
  float4 xc0,xc1,xc2,xc3;                // current quad (!PS, wave 0)
  if (l==0){
    if (PS){
#pragma unroll
      for (int st=0;st<4;++st){
        xh_[st] = *(const uint2v*)(xhp + st*4);
        xl_[st] = *(const uint2v*)(xlp + st*4);
      }
    } else {
      xc0 = *(const float4*)(xp+ 0); xc1 = *(const float4*)(xp+ 4);
      xc2 = *(const float4*)(xp+ 8); xc3 = *(const float4*)(xp+12);
    }
  }

  const int rowW1 = wv*16 + s;
  const short* w1hp = W1h + (size_t)rowW1*3200;
  const short* w1lp = W1l + (size_t)rowW1*3200;
  const float* w1fp = W1  + (size_t)rowW1*3200;

  // ---- hoisted LDS base addresses (ushort units; per-access = base + imm)
  const int laneRd = s*kRow + (q&1)*8;
  const int laneWr = s*kRow + q*4;
  auto OFF = [](int par,int layer,int slot){ return par*kPar + layer*kLay + slot*kSlot; };
  const unsigned short* ra0_0 = H + laneRd + ((q<2) ? OFF(1,lm1,0) : OFF(1,l,3));
  const unsigned short* raS_0 = H + laneRd + ((q<2) ? OFF(1,lm1,1) : OFF(0,l,0));
  unsigned short*       wrt_0 = H + laneWr + OFF(0,l,0);
  const unsigned short* mrd_0 = H + laneRd + OFF(1,3,0) + (q>>1)*kSlot;
  const unsigned short* ra0_1 = H + laneRd + ((q<2) ? OFF(0,lm1,0) : OFF(0,l,3));
  const unsigned short* raS_1 = H + laneRd + ((q<2) ? OFF(0,lm1,1) : OFF(1,l,0));
  unsigned short*       wrt_1 = H + laneWr + OFF(1,l,0);
  const unsigned short* mrd_1 = H + laneRd + OFF(0,3,0) + (q>>1)*kSlot;

  __syncthreads();

  auto super = [&](int n, const unsigned short* ra0, const unsigned short* raS,
                   unsigned short* wa, const unsigned short* ma){
    // ---- 1) W1 load for MLP quad m = n-4 (consumed at bottom of THIS superstep)
    const int m = n - 4;
    FragU WAh0,WAl0,WAh1,WAl1;
    float4 wfa0,wfb0,wfa1,wfb1;
    if (m >= 0 && m < kQ){
      const int off = 64*m + q*8;
      if (PS){
        WAh0.v = *(const bf16x8*)(w1hp + off);
        WAl0.v = *(const bf16x8*)(w1lp + off);
        WAh1.v = *(const bf16x8*)(w1hp + off + 32);
        WAl1.v = *(const bf16x8*)(w1lp + off + 32);
      } else {
        wfa0 = *(const float4*)(w1fp + off);
        wfb0 = *(const float4*)(w1fp + off + 4);
        wfa1 = *(const float4*)(w1fp + off + 32);
        wfb1 = *(const float4*)(w1fp + off + 36);
      }
    }
    const int pr = n - l;                 // this wave's quad
    // ---- 1b) x prefetch for next quad (wave 0)
    uint2v xhn[4], xln[4];
    float4 xn0,xn1,xn2,xn3;
    if (l==0 && pr+1 < kQ){
      if (PS){
#pragma unroll
        for (int st=0;st<4;++st){
          xhn[st] = *(const uint2v*)(xhp + 16*(pr+1) + st*4);
          xln[st] = *(const uint2v*)(xlp + 16*(pr+1) + st*4);
        }
      } else {
        const float* xq = xp + 16*(pr+1);
        xn0 = *(const float4*)(xq+ 0); xn1 = *(const float4*)(xq+ 4);
        xn2 = *(const float4*)(xq+ 8); xn3 = *(const float4*)(xq+12);
      }
    }

    // ---- 2) recurrent layer l, four timesteps of quad pr
    if (pr >= 0 && pr < kQ){
#pragma unroll
      for (int st=0; st<4; ++st){
        const unsigned short* rp_ = (st==0) ? ra0 : (raS + (st-1)*kSlot);
        FragU Bh, Bl;
        Bh.v = *(const bf16x8*)(rp_);
        Bl.v = *(const bf16x8*)(rp_ + 16);
        if (l==0){
          if (q==0){
            if (PS){
              Bh.u[0]=xh_[st][0]; Bh.u[1]=xh_[st][1]; Bh.u[2]=0u; Bh.u[3]=0u;
              Bl.u[0]=xl_[st][0]; Bl.u[1]=xl_[st][1]; Bl.u[2]=0u; Bl.u[3]=0u;
            } else {
              const float4 xv = (st==0)?xc0:(st==1)?xc1:(st==2)?xc2:xc3;
              const unsigned u0=__float_as_uint(xv.x), u1=__float_as_uint(xv.y);
              const unsigned u2=__float_as_uint(xv.z), u3=__float_as_uint(xv.w);
              Bh.u[0] = (u0>>16)|(u1&0xffff0000u);
              Bh.u[1] = (u2>>16)|(u3&0xffff0000u);
              Bh.u[2] = 0u; Bh.u[3] = 0u;
              const float f0 = xv.x-__uint_as_float(u0&0xffff0000u);
              const float f1 = xv.y-__uint_as_float(u1&0xffff0000u);
              const float f2 = xv.z-__uint_as_float(u2&0xffff0000u);
              const float f3 = xv.w-__uint_as_float(u3&0xffff0000u);
              Bl.u[0] = (__float_as_uint(f0)>>16)|(__float_as_uint(f1)&0xffff0000u);
              Bl.u[1] = (__float_as_uint(f2)>>16)|(__float_as_uint(f3)&0xffff0000u);
              Bl.u[2] = 0u; Bl.u[3] = 0u;
            }
          } else if (q==1){
#pragma unroll
            for (int r=0;r<4;++r){ Bh.u[r]=0u; Bl.u[r]=0u; }
          }
        }

        // D[tile][r] = 1 + exp2(gate preact)  (preacts pre-scaled by -log2e
        // for i,f,o and -2log2e for g via weight/bias folding)
        float Dt[4][4];
#pragma unroll
        for (int tile=0;tile<4;++tile){
          f32x4 acc = biasf[tile];
          acc = __builtin_amdgcn_mfma_f32_16x16x32_bf16(A[tile][0].v,Bh.v,acc,0,0,0);
          acc = __builtin_amdgcn_mfma_f32_16x16x32_bf16(A[tile][0].v,Bl.v,acc,0,0,0);
          acc = __builtin_amdgcn_mfma_f32_16x16x32_bf16(A[tile][1].v,Bh.v,acc,0,0,0);
#pragma unroll
          for (int r=0;r<4;++r) Dt[tile][r] = 1.0f + fast_exp2(acc[r]);
        }
        // rational-fused: sig(i)*tanh(g) = (2-Dg)/(Di*Dg);
        //                 sig(o)*tanh(c) = (2-Dc)/(Do*Dc)
        float hn[4];
#pragma unroll
        for (int r=0;r<4;++r){
          const float Rf  = fast_rcp(Dt[1][r]);
          const float Rig = fast_rcp(Dt[0][r]*Dt[2][r]);
          const float ig  = (2.0f - Dt[2][r])*Rig;
          float cn = fmaf(cst[r], Rf, ig);
          cst[r] = cn;
          cn = fminf(fmaxf(cn, -10.0f), 10.0f);   // tanh saturates; avoid inf*0
          const float Ec = fast_exp2(kN2Log2e*cn);
          const float Dc = 1.0f + Ec;
          const float Roc = fast_rcp(Dt[3][r]*Dc);
          hn[r] = (2.0f - Dc)*Roc;
        }
        // producer-side trunc pack -> interleaved hi/lo row
        {
          const unsigned u0=__float_as_uint(hn[0]), u1=__float_as_uint(hn[1]);
          const unsigned u2=__float_as_uint(hn[2]), u3=__float_as_uint(hn[3]);
          const unsigned hi01 = (u0>>16)|(u1&0xffff0000u);
          const unsigned hi23 = (u2>>16)|(u3&0xffff0000u);
          const float f0 = hn[0]-__uint_as_float(u0&0xffff0000u);
          const float f1 = hn[1]-__uint_as_float(u1&0xffff0000u);
          const float f2 = hn[2]-__uint_as_float(u2&0xffff0000u);
          const float f3 = hn[3]-__uint_as_float(u3&0xffff0000u);
          const unsigned lo01 = (__float_as_uint(f0)>>16)|(__float_as_uint(f1)&0xffff0000u);
          const unsigned lo23 = (__float_as_uint(f2)>>16)|(__float_as_uint(f3)&0xffff0000u);
          *(uint2v*)(wa + st*kSlot)      = (uint2v){hi01,hi23};
          *(uint2v*)(wa + st*kSlot + 16) = (uint2v){lo01,lo23};
        }
      }
    }
    if (l==0 && pr+1 < kQ){
      if (PS){
#pragma unroll
        for (int st=0;st<4;++st){ xh_[st]=xhn[st]; xl_[st]=xln[st]; }
      } else { xc0=xn0; xc1=xn1; xc2=xn2; xc3=xn3; }
    }

    // ---- 3) MLP tile wv for quad m: pairs 2m, 2m+1 (K=32 each)
    if (m >= 0 && m < kQ){
#pragma unroll
      for (int pp=0; pp<2; ++pp){
        const unsigned short* bp = ma + pp*(2*kSlot);
        FragU Bh, Bl;
        Bh.v = *(const bf16x8*)(bp);
        Bl.v = *(const bf16x8*)(bp + 16);
        FragU Ah, Al;
        if (PS){
          Ah = pp ? WAh1 : WAh0;
          Al = pp ? WAl1 : WAl0;
        } else {
          const float4 wa4 = pp ? wfa1 : wfa0;
          const float4 wb4 = pp ? wfb1 : wfb0;
          float v[8] = {wa4.x,wa4.y,wa4.z,wa4.w,wb4.x,wb4.y,wb4.z,wb4.w};
          split8(v,Ah,Al);
        }
        mlpacc = __builtin_amdgcn_mfma_f32_16x16x32_bf16(Ah.v,Bh.v,mlpacc,0,0,0);
        mlpacc = __builtin_amdgcn_mfma_f32_16x16x32_bf16(Ah.v,Bl.v,mlpacc,0,0,0);
        mlpacc = __builtin_amdgcn_mfma_f32_16x16x32_bf16(Al.v,Bh.v,mlpacc,0,0,0);
      }
    }
    __syncthreads();
  };

#pragma unroll 1
  for (int n2 = 0; n2 < kSteps/2; ++n2){
    super(2*n2,   ra0_0, raS_0, wrt_0, mrd_0);
    super(2*n2+1, ra0_1, raS_1, wrt_1, mrd_1);
  }

  // ---- epilogue: relu -> ldsR; W2 stage spread over the 4 waves
  {
    f32x4 rv;
#pragma unroll
    for (int r=0;r<4;++r)
      rv[r] = fmaxf(mlpacc[r] + b1[wv*16 + 4*q + r], 0.f);
    *(f32x4*)&ldsR[s][wv*16 + 4*q] = rv;
  }
  __syncthreads();
  {
    const int o  = lane & 31;
    const int oc = (o < kOut) ? o : 0;
    float4 w2r[16];
#pragma unroll
    for (int c2=0;c2<16;++c2) w2r[c2] = *(const float4*)(W2 + oc*64 + 4*c2);
    const float bias2 = b2[oc];
#pragma unroll
    for (int mm=0;mm<2;++mm){
      const int s2 = wv*4 + 2*mm + (lane>>5);
      float a0=bias2, a1=0.f, a2=0.f, a3=0.f;
#pragma unroll
      for (int c2=0;c2<16;++c2){
        const float4 rvv = *(const float4*)&ldsR[s2][4*c2];
        a0 = fmaf(w2r[c2].x, rvv.x, a0);
        a1 = fmaf(w2r[c2].y, rvv.y, a1);
        a2 = fmaf(w2r[c2].z, rvv.z, a2);
        a3 = fmaf(w2r[c2].w, rvv.w, a3);
      }
      if (o < kOut) out[(size_t)(sbase+s2)*kOut + o] = (a0+a1)+(a2+a3);
    }
  }
}

extern "C" void kernel_launch(void* const* d_in, const int* in_sizes, int n_in,
                              void* d_out, int out_size, void* d_ws, size_t ws_size,
                              hipStream_t stream) {
  (void)in_sizes; (void)n_in; (void)out_size;
  const float* x    = (const float*)d_in[0];
  const float* Wih0 = (const float*)d_in[1];
  const float* Wihr = (const float*)d_in[2];
  const float* Whh  = (const float*)d_in[3];
  const float* bih  = (const float*)d_in[4];
  const float* bhh  = (const float*)d_in[5];
  const float* W1   = (const float*)d_in[6];
  const float* b1   = (const float*)d_in[7];
  const float* W2   = (const float*)d_in[8];
  const float* b2   = (const float*)d_in[9];
  float* out = (float*)d_out;

  const size_t needBytes = ((size_t)kW1Elems*2 + (size_t)kXElems*2) * sizeof(short);
  dim3 grid(8192/16), block(256);
  if (ws_size >= needBytes) {
    short* W1h = (short*)d_ws;
    short* W1l = W1h + kW1Elems;
    short* Xh  = W1l + kW1Elems;
    short* Xl  = Xh + kXElems;
    hipLaunchKernelGGL(presplit_pair, dim3((kW1Elems+255)/256), dim3(256), 0, stream,
                       W1, kW1Elems, W1h, W1l);
    hipLaunchKernelGGL(presplit_pair, dim3((kXElems+255)/256), dim3(256), 0, stream,
                       x, kXElems, Xh, Xl);
    hipLaunchKernelGGL(lstm_pipe<true>, grid, block, 0, stream,
                       x, Wih0, Wihr, Whh, bih, bhh, W1, b1, W2, b2,
                       W1h, W1l, Xh, Xl, out);
  } else {
    hipLaunchKernelGGL(lstm_pipe<false>, grid, block, 0, stream,
                       x, Wih0, Wihr, Whh, bih, bhh, W1, b1, W2, b2,
                       (const short*)nullptr, (const short*)nullptr,
                       (const short*)nullptr, (const short*)nullptr, out);
  }
}